// Round 5
// baseline (14217.871 us; speedup 1.0000x reference)
//
#include <hip/hip_runtime.h>
#include <stdint.h>

#define NU 4096
#define NB 2048
#define KK2 8192
#define ITERS 100
#define CAP 262144
#define THETA 0.05f
#define KC 512              // host fixup k-panel (verified)

// ws layout (bytes) — unchanged
#define OFF_BT   0u
#define OFF_A0   67108864u
#define OFF_A1   83886080u
#define OFF_SUS  100663296u
#define OFF_CNT  102760448u
#define REQ_WS   102761472u

// GEMM geometry: BM=256 x BN=128, 512 thr (8 waves 4Mx2N, wave-tile 64x64).
// BK=32, 128 K-tiles. Per tile: cluster hi (af x Bhi) + cluster lo (af x Blo)
// — A fragments reused across the W_hi/W_lo split (A read & staged once).
// 4-deep LDS rotation, 32 KB/slab (A 16K @+0, Bhi 8K @+16384, Blo 8K @+24576).
// ALL fragment reads for tile k+1 are primed during tile k (its buffer was
// staged during k-1, published at the k-1->k barrier). Tile boundaries carry
// zero ds_reads; vmcnt(0) retires gl16s issued a full tile earlier (free).
// 64B LDS rows => linear layout is conflict-free for gl16 writes (1KB
// contiguous/wave) and b128 reads (64 lanes tile 1KB contiguous). No swizzle.
#define NT 128

typedef float f32x4 __attribute__((ext_vector_type(4)));
typedef __bf16 bf16x8 __attribute__((ext_vector_type(8)));

__device__ __forceinline__ unsigned short f2bf(float x) {
  unsigned u = __float_as_uint(x);
  u += 0x7FFFu + ((u >> 16) & 1u);
  return (unsigned short)(u >> 16);
}
__device__ __forceinline__ float bf2f(unsigned short h) {
  return __uint_as_float(((unsigned)h) << 16);
}

__device__ __forceinline__ void gl16(const unsigned short* g, char* l) {
  __builtin_amdgcn_global_load_lds(
      (const __attribute__((address_space(1))) unsigned int*)g,
      (__attribute__((address_space(3))) unsigned int*)l, 16, 0, 0);
}

__global__ void fill_kernel(float* __restrict__ out, float v) {
  int t = blockIdx.x * blockDim.x + threadIdx.x;
  int base = t << 3;
  float4 a = make_float4(v, v, v, v);
  *(float4*)(out + base) = a;
  *(float4*)(out + base + 4) = a;
}

__global__ void decompose_kernel(const float* __restrict__ W,
                                 unsigned short* __restrict__ Bt) {
  int t = blockIdx.x * blockDim.x + threadIdx.x;
  int base = t << 2;
  int j = base >> 12;
  int k = base & 4095;
  float4 w = *(const float4*)(W + (size_t)j * NU + k);
  unsigned short h0 = f2bf(w.x), h1 = f2bf(w.y), h2 = f2bf(w.z), h3 = f2bf(w.w);
  ushort4 hi = make_ushort4(h0, h1, h2, h3);
  ushort4 lo = make_ushort4(f2bf(w.x - bf2f(h0)), f2bf(w.y - bf2f(h1)),
                            f2bf(w.z - bf2f(h2)), f2bf(w.w - bf2f(h3)));
  *(ushort4*)(Bt + (size_t)j * KK2 + k) = hi;
  *(ushort4*)(Bt + (size_t)j * KK2 + NU + k) = lo;
}

// Initial state: P (fp32 +-1, exact) -> A0 bf16 +-1.
__global__ void init_kernel(const float* __restrict__ P,
                            unsigned short* __restrict__ A0) {
  int t = blockIdx.x * blockDim.x + threadIdx.x;
  int base = t << 3;
  float4 a = *(const float4*)(P + base);
  float4 b = *(const float4*)(P + base + 4);
  float hv[8] = {a.x, a.y, a.z, a.w, b.x, b.y, b.z, b.w};
  uint4 pk;
  unsigned short s[8];
#pragma unroll
  for (int i = 0; i < 8; ++i)
    s[i] = (hv[i] >= 0.0f) ? (unsigned short)0x3F80u : (unsigned short)0xBF80u;
  pk.x = (unsigned)s[0] | ((unsigned)s[1] << 16);
  pk.y = (unsigned)s[2] | ((unsigned)s[3] << 16);
  pk.z = (unsigned)s[4] | ((unsigned)s[5] << 16);
  pk.w = (unsigned)s[6] | ((unsigned)s[7] << 16);
  *(uint4*)(A0 + base) = pk;
}

// ---- schedule primitives ----
#define SCB() __builtin_amdgcn_sched_barrier(0)
#define BAR() do { __builtin_amdgcn_sched_barrier(0);          \
                   __builtin_amdgcn_s_barrier();               \
                   __builtin_amdgcn_sched_barrier(0); } while (0)
#define VM0() do { asm volatile("s_waitcnt vmcnt(0)" ::: "memory");    \
                   __builtin_amdgcn_sched_barrier(0); } while (0)
#define MM(AF, BF) do { __builtin_amdgcn_s_setprio(1);                       \
  _Pragma("unroll") for (int i_ = 0; i_ < 4; ++i_)                           \
  _Pragma("unroll") for (int j_ = 0; j_ < 4; ++j_)                           \
    acc[i_][j_] = __builtin_amdgcn_mfma_f32_16x16x32_bf16(                   \
        AF[i_], BF[j_], acc[i_][j_], 0, 0, 0);                               \
  __builtin_amdgcn_s_setprio(0); } while (0)
#define RD4S(DST, BASE) _Pragma("unroll")                                     \
  for (int q_ = 0; q_ < 4; ++q_)                                              \
    DST[q_] = *(const bf16x8*)((BASE) + q_ * 1024);

// One K-tile body. k: tile index; bufN: slab of tile k+1 (prime source);
// bufS: slab of tile k+2 (staging dest). CF*: compute fragment set (primed
// during tile k-1); PF*: fragment set primed here for tile k+1.
// Ledger: reads of slab j happen only during tile j-1 (primes); slab j is
// rewritten by staging during tile j+2 — two publish barriers apart. Staging
// issued during tile k is retired by each wave's own vmcnt(0) at tile k end,
// then the barrier publishes it; primes of tile k+2 (which read it) run
// during tile k+1, strictly after. Guards depend on k only (block-uniform).
#define TB(k, bufN, bufS, CFa, CFh, CFl, PFa, PFh, PFl)                       \
  {                                                                           \
    const int kS_ = ((k) + 2) << 5;                                           \
    if ((k) + 2 < NT) {                                                       \
      gl16(pAs + kS_, (bufS) + ldsA);                                         \
      gl16(pAs2 + kS_, (bufS) + ldsA + 1024);                                 \
      gl16(pBsH + kS_, (bufS) + 16384 + ldsB);                                \
      gl16(pBsL + kS_, (bufS) + 24576 + ldsB);                                \
    }                                                                         \
    SCB();                                                                    \
    MM(CFa, CFh);                                                             \
    SCB();                                                                    \
    if ((k) + 1 < NT) {                                                       \
      RD4S(PFa, (bufN) + aOff);                                               \
      RD4S(PFh, (bufN) + 16384 + bOff);                                       \
    }                                                                         \
    SCB();                                                                    \
    MM(CFa, CFl);                                                             \
    SCB();                                                                    \
    if ((k) + 1 < NT) { RD4S(PFl, (bufN) + 24576 + bOff); }                   \
    SCB();                                                                    \
    VM0();                                                                    \
    BAR();                                                                    \
  }

__global__ void __launch_bounds__(512, 1)
gemm_fused_kernel(const unsigned short* __restrict__ A,
                  const unsigned short* __restrict__ Bt,
                  unsigned short* __restrict__ Anext,
                  float* __restrict__ outF, int writeOut,
                  int* __restrict__ counter,
                  int* __restrict__ suspects) {
  __shared__ __align__(16) unsigned short sL[65536];   // 131072 B = 4 x 32KB
  const int tid = threadIdx.x;
  const int wave = tid >> 6, lane = tid & 63;
  const int lm = lane & 15, lk = lane >> 4;
  const int wm = wave >> 1, wn = wave & 1;             // 4M x 2N wave grid
  const int nt = blockIdx.x & 31, mt = blockIdx.x >> 5;
  const int mBase = mt << 8, nBase = nt << 7;

  // ---- staging lane constants (all linear; conflict-free by construction) --
  const int rl = lane >> 2;                            // 0..15 rows
  const int cs = (lane & 3) << 3;                      // 0/8/16/24 elems
  const unsigned short* pAs = A + (size_t)(mBase + (wave << 5) + rl) * NU + cs;
  const unsigned short* pAs2 = pAs + (size_t)16 * NU;
  const unsigned short* pBsH = Bt + (size_t)(nBase + (wave << 4) + rl) * KK2 + cs;
  const unsigned short* pBsL = pBsH + NU;
  const int ldsA = wave << 11;                         // wave*2048 (A: 2 gl16)
  const int ldsB = wave << 10;                         // wave*1024 (B: 1 gl16)
  char* sb0 = (char*)sL;
  char* sb1 = sb0 + 32768;
  char* sb2 = sb0 + 65536;
  char* sb3 = sb0 + 98304;

  // ---- fragment-read lane constants (rows are 64B; slice = lk*16 bytes) ----
  const int aOff = (((wm << 6) + lm) << 6) + (lk << 4);
  const int bOff = (((wn << 6) + lm) << 6) + (lk << 4);

  f32x4 acc[4][4] = {};
  bf16x8 afA[4], bhA[4], blA[4], afB[4], bhB[4], blB[4];

  // prologue: stage tiles 0,1 -> slabs 0,1; publish; prime tile 0 into set A
  gl16(pAs, sb0 + ldsA);        gl16(pAs2, sb0 + ldsA + 1024);
  gl16(pBsH, sb0 + 16384 + ldsB); gl16(pBsL, sb0 + 24576 + ldsB);
  gl16(pAs + 32, sb1 + ldsA);   gl16(pAs2 + 32, sb1 + ldsA + 1024);
  gl16(pBsH + 32, sb1 + 16384 + ldsB); gl16(pBsL + 32, sb1 + 24576 + ldsB);
  VM0();
  BAR();
  RD4S(afA, sb0 + aOff);
  RD4S(bhA, sb0 + 16384 + bOff);
  RD4S(blA, sb0 + 24576 + bOff);

  for (int kb = 0; kb < NT; kb += 4) {
    TB(kb + 0, sb1, sb2, afA, bhA, blA, afB, bhB, blB);
    TB(kb + 1, sb2, sb3, afB, bhB, blB, afA, bhA, blA);
    TB(kb + 2, sb3, sb0, afA, bhA, blA, afB, bhB, blB);
    TB(kb + 3, sb0, sb1, afB, bhB, blB, afA, bhA, blA);
  }

  // Fused sign epilogue. C/D layout (m89/m91): col=lane&15, row=(lane>>4)*4+reg
#pragma unroll
  for (int i = 0; i < 4; ++i)
#pragma unroll
    for (int j = 0; j < 4; ++j)
#pragma unroll
      for (int r = 0; r < 4; ++r) {
        const int row = mBase + (wm << 6) + i * 16 + (lk << 2) + r;
        const int col = nBase + (wn << 6) + j * 16 + lm;
        const float h = acc[i][j][r];
        Anext[(size_t)row * NU + col] =
            (h >= 0.0f) ? (unsigned short)0x3F80u : (unsigned short)0xBF80u;
        if (fabsf(h) < THETA) {
          int idx = atomicAdd(counter, 1);
          if (idx < CAP) suspects[idx] = (row << 12) | col;
        }
        if (writeOut)
          outF[(size_t)row * NU + col] = (h >= 0.0f) ? 1.0f : -1.0f;
      }
}

// Suspects, 8 lanes per suspect (one per KC=512 panel). Same sequential fp32
// chain as the round-8-verified version; bitwise-identical sign decision.
__global__ void fixup_kernel(const unsigned short* __restrict__ Acur,
                             const float* __restrict__ W,
                             unsigned short* __restrict__ Anext,
                             float* __restrict__ outF, int writeOut,
                             const int* __restrict__ counter,
                             const int* __restrict__ suspects,
                             int* __restrict__ flagOv) {
  int n = *counter;
  if (blockIdx.x == 0 && threadIdx.x == 0 && n > CAP) atomicAdd(flagOv, 1);
  n = n < CAP ? n : CAP;
  const int lane = threadIdx.x & 7;                       // panel index
  const int gid = (blockIdx.x * blockDim.x + threadIdx.x) >> 3;
  const int ngrp = (gridDim.x * blockDim.x) >> 3;
  for (int i = gid; i < n; i += ngrp) {
    int idx = suspects[i];
    int b = idx >> 12, j = idx & 4095;
    const float* wrow = W + (size_t)j * NU + lane * KC;
    const unsigned short* arow = Acur + (size_t)b * NU + lane * KC;
    float part = 0.0f;
    for (int k = 0; k < KC; k += 4) {
      float4 wv = *(const float4*)(wrow + k);
      ushort4 av = *(const ushort4*)(arow + k);
      part += (av.x & 0x8000) ? -wv.x : wv.x;
      part += (av.y & 0x8000) ? -wv.y : wv.y;
      part += (av.z & 0x8000) ? -wv.z : wv.z;
      part += (av.w & 0x8000) ? -wv.w : wv.w;
    }
    float c = __shfl(part, 0, 8);
#pragma unroll
    for (int q = 1; q < 8; ++q) c += __shfl(part, q, 8);
    if (lane == 0) {
      Anext[(size_t)b * NU + j] =
          (c >= 0.0f) ? (unsigned short)0x3F80u : (unsigned short)0xBF80u;
      if (writeOut) outF[(size_t)b * NU + j] = (c >= 0.0f) ? 1.0f : -1.0f;
    }
  }
}

// Tripwire: if the suspect list ever overflows, poison the output signature.
__global__ void assemble_kernel(float* __restrict__ out,
                                const int* __restrict__ flags) {
  if (threadIdx.x != 0 || blockIdx.x != 0) return;
  if (flags[1]) out[0] = 7777.0f;
}

extern "C" void kernel_launch(void* const* d_in, const int* in_sizes, int n_in,
                              void* d_out, int out_size, void* d_ws, size_t ws_size,
                              hipStream_t stream) {
  const float* P = (const float*)d_in[0];
  const float* W = (const float*)d_in[1];
  float* out = (float*)d_out;

  if (n_in < 2 || in_sizes[0] != NB * NU || in_sizes[1] != NU * NU ||
      out_size != NB * NU) {
    fill_kernel<<<4096, 256, 0, stream>>>(out, 9.0f);
    return;
  }
  if (ws_size < (size_t)REQ_WS) {
    fill_kernel<<<4096, 256, 0, stream>>>(out, 3.0f);
    return;
  }

  char* w = (char*)d_ws;
  unsigned short* Bt = (unsigned short*)(w + OFF_BT);
  unsigned short* A0 = (unsigned short*)(w + OFF_A0);
  unsigned short* A1 = (unsigned short*)(w + OFF_A1);
  int* suspects = (int*)(w + OFF_SUS);
  int* counters = (int*)(w + OFF_CNT);
  int* flags = counters + 128;  // [1]=suspect overflow

  hipMemsetAsync(counters, 0, 1024, stream);
  decompose_kernel<<<16384, 256, 0, stream>>>(W, Bt);
  init_kernel<<<4096, 256, 0, stream>>>(P, A0);

  for (int t = 0; t < ITERS; ++t) {
    unsigned short* Ain = (t & 1) ? A1 : A0;
    unsigned short* Aout = (t & 1) ? A0 : A1;
    int fin = (t == ITERS - 1) ? 1 : 0;
    gemm_fused_kernel<<<256, 512, 0, stream>>>(Ain, Bt, Aout, out, fin,
                                               &counters[t], suspects);
    fixup_kernel<<<256, 256, 0, stream>>>(Ain, W, Aout, out, fin,
                                          &counters[t], suspects, &flags[1]);
  }
  assemble_kernel<<<1, 64, 0, stream>>>(out, flags);
}

// Round 6
// 13621.658 us; speedup vs baseline: 1.0438x; 1.0438x over previous
//
#include <hip/hip_runtime.h>
#include <stdint.h>

#define NU 4096
#define NB 2048
#define KK2 8192
#define ITERS 100
#define CAP 262144
#define THETA 0.05f
#define KC 512              // host fixup k-panel (verified)

// ws layout (bytes) — unchanged
#define OFF_BT   0u
#define OFF_A0   67108864u
#define OFF_A1   83886080u
#define OFF_SUS  100663296u
#define OFF_CNT  102760448u
#define REQ_WS   102761472u

// GEMM geometry: BM=256 x BN=128, 512 thr (8 waves 4Mx2N, wave-tile 64x64).
// BK=32, 128 K-tiles; per tile cluster hi (af x Bhi) + lo (af x Blo), A
// fragments reused across the W_hi/W_lo split. 4-deep LDS rotation, 32KB/slab
// (A 16K @+0, Bhi 8K @+16384, Blo 8K @+24576). All fragment reads for tile
// k+1 primed during tile k; staging is 3 tiles ahead with COUNTED vmcnt(4)
// in steady state (never 0 mid-loop).
// SLOT SWIZZLE (round-5 fix): logical 16B slot sl of row r lives at phys slot
// (sl + (r>>1)) & 3. Applied on the GLOBAL source column at staging (LDS dest
// linear for gl16) and on the ds_read phys slot. Quarter-wave (fixed lk,
// lm=0..15) bank-group pattern 4(lm&1) + ((lk+(lm>>1))&3) covers all 8
// groups exactly twice = b128 optimum (the round-1..4 zero-conflict shape).
#define NT 128

typedef float f32x4 __attribute__((ext_vector_type(4)));
typedef __bf16 bf16x8 __attribute__((ext_vector_type(8)));

__device__ __forceinline__ unsigned short f2bf(float x) {
  unsigned u = __float_as_uint(x);
  u += 0x7FFFu + ((u >> 16) & 1u);
  return (unsigned short)(u >> 16);
}
__device__ __forceinline__ float bf2f(unsigned short h) {
  return __uint_as_float(((unsigned)h) << 16);
}

__device__ __forceinline__ void gl16(const unsigned short* g, char* l) {
  __builtin_amdgcn_global_load_lds(
      (const __attribute__((address_space(1))) unsigned int*)g,
      (__attribute__((address_space(3))) unsigned int*)l, 16, 0, 0);
}

__global__ void fill_kernel(float* __restrict__ out, float v) {
  int t = blockIdx.x * blockDim.x + threadIdx.x;
  int base = t << 3;
  float4 a = make_float4(v, v, v, v);
  *(float4*)(out + base) = a;
  *(float4*)(out + base + 4) = a;
}

__global__ void decompose_kernel(const float* __restrict__ W,
                                 unsigned short* __restrict__ Bt) {
  int t = blockIdx.x * blockDim.x + threadIdx.x;
  int base = t << 2;
  int j = base >> 12;
  int k = base & 4095;
  float4 w = *(const float4*)(W + (size_t)j * NU + k);
  unsigned short h0 = f2bf(w.x), h1 = f2bf(w.y), h2 = f2bf(w.z), h3 = f2bf(w.w);
  ushort4 hi = make_ushort4(h0, h1, h2, h3);
  ushort4 lo = make_ushort4(f2bf(w.x - bf2f(h0)), f2bf(w.y - bf2f(h1)),
                            f2bf(w.z - bf2f(h2)), f2bf(w.w - bf2f(h3)));
  *(ushort4*)(Bt + (size_t)j * KK2 + k) = hi;
  *(ushort4*)(Bt + (size_t)j * KK2 + NU + k) = lo;
}

// Initial state: P (fp32 +-1, exact) -> A0 bf16 +-1.
__global__ void init_kernel(const float* __restrict__ P,
                            unsigned short* __restrict__ A0) {
  int t = blockIdx.x * blockDim.x + threadIdx.x;
  int base = t << 3;
  float4 a = *(const float4*)(P + base);
  float4 b = *(const float4*)(P + base + 4);
  float hv[8] = {a.x, a.y, a.z, a.w, b.x, b.y, b.z, b.w};
  uint4 pk;
  unsigned short s[8];
#pragma unroll
  for (int i = 0; i < 8; ++i)
    s[i] = (hv[i] >= 0.0f) ? (unsigned short)0x3F80u : (unsigned short)0xBF80u;
  pk.x = (unsigned)s[0] | ((unsigned)s[1] << 16);
  pk.y = (unsigned)s[2] | ((unsigned)s[3] << 16);
  pk.z = (unsigned)s[4] | ((unsigned)s[5] << 16);
  pk.w = (unsigned)s[6] | ((unsigned)s[7] << 16);
  *(uint4*)(A0 + base) = pk;
}

// ---- schedule primitives ----
#define SCB() __builtin_amdgcn_sched_barrier(0)
#define BAR() do { __builtin_amdgcn_sched_barrier(0);          \
                   __builtin_amdgcn_s_barrier();               \
                   __builtin_amdgcn_sched_barrier(0); } while (0)
#define VM0() do { asm volatile("s_waitcnt vmcnt(0)" ::: "memory");    \
                   __builtin_amdgcn_sched_barrier(0); } while (0)
#define VM4() do { asm volatile("s_waitcnt vmcnt(4)" ::: "memory");    \
                   __builtin_amdgcn_sched_barrier(0); } while (0)
#define MM(AF, BF) do { __builtin_amdgcn_s_setprio(1);                       \
  _Pragma("unroll") for (int i_ = 0; i_ < 4; ++i_)                           \
  _Pragma("unroll") for (int j_ = 0; j_ < 4; ++j_)                           \
    acc[i_][j_] = __builtin_amdgcn_mfma_f32_16x16x32_bf16(                   \
        AF[i_], BF[j_], acc[i_][j_], 0, 0, 0);                               \
  __builtin_amdgcn_s_setprio(0); } while (0)
#define RD4S(DST, BASE) _Pragma("unroll")                                     \
  for (int q_ = 0; q_ < 4; ++q_)                                              \
    DST[q_] = *(const bf16x8*)((BASE) + q_ * 1024);

// One K-tile body. bufN: slab of tile k+1 (prime source, slab (k+1)&3);
// bufS: slab of tile k+3 (staging dest, slab (k+3)&3). CF*: compute set
// (primed during k-1); PF*: set primed here for k+1.
// vmcnt ledger (per wave, 4 gl16/tile): end of tile k outstanding =
// {k+3 (issued now), k+2 (issued at k-1)} = 8 -> vmcnt(4) retires exactly
// k+2's, published at the k->k+1 barrier, primed during k+1. k=0: 4
// outstanding -> vmcnt(4) free (slab 2 already published in prologue).
// Tail k>=NT-3: vmcnt(0). Slab hazard: slab j primed during j-1 (reads
// retire via compiler lgkm-waits before tile-j MFMAs -> before the j->j+1
// barrier), rewritten during j+1 -> ordered. Guards block-uniform.
#define TB(k, bufN, bufS, CFa, CFh, CFl, PFa, PFh, PFl)                       \
  {                                                                           \
    const int kS_ = ((k) + 3) << 5;                                           \
    if ((k) + 3 < NT) {                                                       \
      gl16(pAs + kS_, (bufS) + ldsA);                                         \
      gl16(pAs2 + kS_, (bufS) + ldsA + 1024);                                 \
      gl16(pBsH + kS_, (bufS) + 16384 + ldsB);                                \
      gl16(pBsL + kS_, (bufS) + 24576 + ldsB);                                \
    }                                                                         \
    SCB();                                                                    \
    MM(CFa, CFh);                                                             \
    SCB();                                                                    \
    if ((k) + 1 < NT) {                                                       \
      RD4S(PFa, (bufN) + aOff);                                               \
      RD4S(PFh, (bufN) + 16384 + bOff);                                       \
    }                                                                         \
    SCB();                                                                    \
    MM(CFa, CFl);                                                             \
    SCB();                                                                    \
    if ((k) + 1 < NT) { RD4S(PFl, (bufN) + 24576 + bOff); }                   \
    SCB();                                                                    \
    if ((k) < NT - 3) { VM4(); } else { VM0(); }                              \
    BAR();                                                                    \
  }

__global__ void __launch_bounds__(512, 1)
gemm_fused_kernel(const unsigned short* __restrict__ A,
                  const unsigned short* __restrict__ Bt,
                  unsigned short* __restrict__ Anext,
                  float* __restrict__ outF, int writeOut,
                  int* __restrict__ counter,
                  int* __restrict__ suspects) {
  __shared__ __align__(16) unsigned short sL[65536];   // 131072 B = 4 x 32KB
  const int tid = threadIdx.x;
  const int wave = tid >> 6, lane = tid & 63;
  const int lm = lane & 15, lk = lane >> 4;
  const int wm = wave >> 1, wn = wave & 1;             // 4M x 2N wave grid
  const int nt = blockIdx.x & 31, mt = blockIdx.x >> 5;
  const int mBase = mt << 8, nBase = nt << 7;

  // ---- staging lane constants ----
  // LDS dest linear (wave base + lane*16). Global source column carries the
  // INVERSE slot swizzle: phys slot s=lane&3 at row r holds logical slot
  // (s - (r>>1))&3; (r>>1)&3 == (lane>>3)&3 for both A (32-row) and B
  // (16-row) staging chunks (wave-base terms are ==0 mod 4).
  const int rl = lane >> 2;                            // 0..15 rows
  const int cs = ((((lane & 3) - ((lane >> 3) & 3)) & 3) << 3);  // elems
  const unsigned short* pAs = A + (size_t)(mBase + (wave << 5) + rl) * NU + cs;
  const unsigned short* pAs2 = pAs + (size_t)16 * NU;
  const unsigned short* pBsH = Bt + (size_t)(nBase + (wave << 4) + rl) * KK2 + cs;
  const unsigned short* pBsL = pBsH + NU;
  const int ldsA = wave << 11;                         // wave*2048 (A: 2 gl16)
  const int ldsB = wave << 10;                         // wave*1024 (B: 1 gl16)
  char* sb0 = (char*)sL;
  char* sb1 = sb0 + 32768;
  char* sb2 = sb0 + 65536;
  char* sb3 = sb0 + 98304;

  // ---- fragment-read lane constants ----
  // phys slot = (lk + (r>>1))&3; (r>>1)&3 == (lm>>1)&3 (wm*32, q*8 == 0 mod 4)
  const int pslot = (lk + ((lm >> 1) & 3)) & 3;
  const int aOff = (((wm << 6) + lm) << 6) + (pslot << 4);
  const int bOff = (((wn << 6) + lm) << 6) + (pslot << 4);

  f32x4 acc[4][4] = {};
  bf16x8 afA[4], bhA[4], blA[4], afB[4], bhB[4], blB[4];

  // prologue: stage tiles 0,1,2 -> slabs 0,1,2; publish; prime tile 0 (set A)
  gl16(pAs, sb0 + ldsA);          gl16(pAs2, sb0 + ldsA + 1024);
  gl16(pBsH, sb0 + 16384 + ldsB); gl16(pBsL, sb0 + 24576 + ldsB);
  gl16(pAs + 32, sb1 + ldsA);     gl16(pAs2 + 32, sb1 + ldsA + 1024);
  gl16(pBsH + 32, sb1 + 16384 + ldsB); gl16(pBsL + 32, sb1 + 24576 + ldsB);
  gl16(pAs + 64, sb2 + ldsA);     gl16(pAs2 + 64, sb2 + ldsA + 1024);
  gl16(pBsH + 64, sb2 + 16384 + ldsB); gl16(pBsL + 64, sb2 + 24576 + ldsB);
  VM0();
  BAR();
  RD4S(afA, sb0 + aOff);
  RD4S(bhA, sb0 + 16384 + bOff);
  RD4S(blA, sb0 + 24576 + bOff);

  for (int kb = 0; kb < NT; kb += 4) {
    TB(kb + 0, sb1, sb3, afA, bhA, blA, afB, bhB, blB);
    TB(kb + 1, sb2, sb0, afB, bhB, blB, afA, bhA, blA);
    TB(kb + 2, sb3, sb1, afA, bhA, blA, afB, bhB, blB);
    TB(kb + 3, sb0, sb2, afB, bhB, blB, afA, bhA, blA);
  }

  // Fused sign epilogue. C/D layout (m89/m91): col=lane&15, row=(lane>>4)*4+reg
#pragma unroll
  for (int i = 0; i < 4; ++i)
#pragma unroll
    for (int j = 0; j < 4; ++j)
#pragma unroll
      for (int r = 0; r < 4; ++r) {
        const int row = mBase + (wm << 6) + i * 16 + (lk << 2) + r;
        const int col = nBase + (wn << 6) + j * 16 + lm;
        const float h = acc[i][j][r];
        Anext[(size_t)row * NU + col] =
            (h >= 0.0f) ? (unsigned short)0x3F80u : (unsigned short)0xBF80u;
        if (fabsf(h) < THETA) {
          int idx = atomicAdd(counter, 1);
          if (idx < CAP) suspects[idx] = (row << 12) | col;
        }
        if (writeOut)
          outF[(size_t)row * NU + col] = (h >= 0.0f) ? 1.0f : -1.0f;
      }
}

// Suspects, 8 lanes per suspect (one per KC=512 panel). Same sequential fp32
// chain as the round-8-verified version; bitwise-identical sign decision.
__global__ void fixup_kernel(const unsigned short* __restrict__ Acur,
                             const float* __restrict__ W,
                             unsigned short* __restrict__ Anext,
                             float* __restrict__ outF, int writeOut,
                             const int* __restrict__ counter,
                             const int* __restrict__ suspects,
                             int* __restrict__ flagOv) {
  int n = *counter;
  if (blockIdx.x == 0 && threadIdx.x == 0 && n > CAP) atomicAdd(flagOv, 1);
  n = n < CAP ? n : CAP;
  const int lane = threadIdx.x & 7;                       // panel index
  const int gid = (blockIdx.x * blockDim.x + threadIdx.x) >> 3;
  const int ngrp = (gridDim.x * blockDim.x) >> 3;
  for (int i = gid; i < n; i += ngrp) {
    int idx = suspects[i];
    int b = idx >> 12, j = idx & 4095;
    const float* wrow = W + (size_t)j * NU + lane * KC;
    const unsigned short* arow = Acur + (size_t)b * NU + lane * KC;
    float part = 0.0f;
    for (int k = 0; k < KC; k += 4) {
      float4 wv = *(const float4*)(wrow + k);
      ushort4 av = *(const ushort4*)(arow + k);
      part += (av.x & 0x8000) ? -wv.x : wv.x;
      part += (av.y & 0x8000) ? -wv.y : wv.y;
      part += (av.z & 0x8000) ? -wv.z : wv.z;
      part += (av.w & 0x8000) ? -wv.w : wv.w;
    }
    float c = __shfl(part, 0, 8);
#pragma unroll
    for (int q = 1; q < 8; ++q) c += __shfl(part, q, 8);
    if (lane == 0) {
      Anext[(size_t)b * NU + j] =
          (c >= 0.0f) ? (unsigned short)0x3F80u : (unsigned short)0xBF80u;
      if (writeOut) outF[(size_t)b * NU + j] = (c >= 0.0f) ? 1.0f : -1.0f;
    }
  }
}

// Tripwire: if the suspect list ever overflows, poison the output signature.
__global__ void assemble_kernel(float* __restrict__ out,
                                const int* __restrict__ flags) {
  if (threadIdx.x != 0 || blockIdx.x != 0) return;
  if (flags[1]) out[0] = 7777.0f;
}

extern "C" void kernel_launch(void* const* d_in, const int* in_sizes, int n_in,
                              void* d_out, int out_size, void* d_ws, size_t ws_size,
                              hipStream_t stream) {
  const float* P = (const float*)d_in[0];
  const float* W = (const float*)d_in[1];
  float* out = (float*)d_out;

  if (n_in < 2 || in_sizes[0] != NB * NU || in_sizes[1] != NU * NU ||
      out_size != NB * NU) {
    fill_kernel<<<4096, 256, 0, stream>>>(out, 9.0f);
    return;
  }
  if (ws_size < (size_t)REQ_WS) {
    fill_kernel<<<4096, 256, 0, stream>>>(out, 3.0f);
    return;
  }

  char* w = (char*)d_ws;
  unsigned short* Bt = (unsigned short*)(w + OFF_BT);
  unsigned short* A0 = (unsigned short*)(w + OFF_A0);
  unsigned short* A1 = (unsigned short*)(w + OFF_A1);
  int* suspects = (int*)(w + OFF_SUS);
  int* counters = (int*)(w + OFF_CNT);
  int* flags = counters + 128;  // [1]=suspect overflow

  hipMemsetAsync(counters, 0, 1024, stream);
  decompose_kernel<<<16384, 256, 0, stream>>>(W, Bt);
  init_kernel<<<4096, 256, 0, stream>>>(P, A0);

  for (int t = 0; t < ITERS; ++t) {
    unsigned short* Ain = (t & 1) ? A1 : A0;
    unsigned short* Aout = (t & 1) ? A0 : A1;
    int fin = (t == ITERS - 1) ? 1 : 0;
    gemm_fused_kernel<<<256, 512, 0, stream>>>(Ain, Bt, Aout, out, fin,
                                               &counters[t], suspects);
    fixup_kernel<<<256, 256, 0, stream>>>(Ain, W, Aout, out, fin,
                                          &counters[t], suspects, &flags[1]);
  }
  assemble_kernel<<<1, 64, 0, stream>>>(out, flags);
}